// Round 1
// 753.926 us; speedup vs baseline: 1.0912x; 1.0912x over previous
//
#include <hip/hip_runtime.h>

typedef unsigned short u16;
typedef __attribute__((ext_vector_type(8))) short bf16x8;
typedef __attribute__((ext_vector_type(4))) float f32x4;

__device__ __forceinline__ u16 f2b(float f) {
  unsigned u = __float_as_uint(f);
  u += 0x7fffu + ((u >> 16) & 1u);
  return (u16)(u >> 16);
}
__device__ __forceinline__ float b2f(u16 v) {
  return __uint_as_float((unsigned)v << 16);
}

// async global -> LDS, 16B per lane. LDS dest must be wave-uniform base; HW adds lane*16.
__device__ __forceinline__ void gload16(const u16* g, u16* l) {
  __builtin_amdgcn_global_load_lds((__attribute__((address_space(1))) void*)(g),
                                   (__attribute__((address_space(3))) void*)(l), 16, 0, 0);
}

// ---------------- cast fp32 -> bf16 (vectorized) ----------------
__global__ __launch_bounds__(256) void cast_k(const float* __restrict__ s,
                                              u16* __restrict__ d, int n4) {
  int i = blockIdx.x * 256 + threadIdx.x;
  if (i >= n4) return;
  float4 v = *(const float4*)(s + (size_t)i * 4);
  ushort4 o = make_ushort4(f2b(v.x), f2b(v.y), f2b(v.z), f2b(v.w));
  *(ushort4*)(d + (size_t)i * 4) = o;
}

// ---------------- fp32 [R x C] -> bf16 transposed [C x R] ----------------
__global__ __launch_bounds__(256) void transpose_k(const float* __restrict__ src,
                                                   u16* __restrict__ dst,
                                                   int ldsrc, int lddst) {
  __shared__ float t[32][33];
  int c0 = blockIdx.x * 32, r0 = blockIdx.y * 32;
  int tx = threadIdx.x, ty = threadIdx.y;
#pragma unroll
  for (int i = 0; i < 4; ++i)
    t[ty + i * 8][tx] = src[(size_t)(r0 + ty + i * 8) * ldsrc + c0 + tx];
  __syncthreads();
#pragma unroll
  for (int i = 0; i < 4; ++i)
    dst[(size_t)(c0 + ty + i * 8) * lddst + r0 + tx] = f2b(t[tx][ty + i * 8]);
}

// ---------------- V head-transpose: qkv[(b*S+s)*3072 + 2048 + h*64 + d] -> vt[bh][d][s]
__global__ __launch_bounds__(256) void transpose_v_k(const u16* __restrict__ qkv,
                                                     u16* __restrict__ vt) {
  __shared__ u16 t[32][33];
  int z = blockIdx.z;
  int b = z >> 4, h = z & 15;
  int s0 = blockIdx.x * 32, d0 = blockIdx.y * 32;
  int tx = threadIdx.x, ty = threadIdx.y;
  const u16* src = qkv + (size_t)(b * 1024) * 3072 + 2048 + h * 64;
  u16* dst = vt + (size_t)z * 65536;
#pragma unroll
  for (int i = 0; i < 4; ++i)
    t[ty + i * 8][tx] = src[(size_t)(s0 + ty + i * 8) * 3072 + d0 + tx];
  __syncthreads();
#pragma unroll
  for (int i = 0; i < 4; ++i)
    dst[(size_t)(d0 + ty + i * 8) * 1024 + s0 + tx] = t[tx][ty + i * 8];
}

// ---------------- GEMM: C[M,N] = A[M,K] * Bt[N,K]^T  (m97 structure)
// Block 256 thr = 4 waves (2x2), tile 128 x BN, BK=64, global_load_lds staging,
// linear LDS [rows][64]. MFMA 16x16x32 bf16.
// Epilogue variants: +bias, relu, exp(v/8) (scores), row-scale (ctx normalize).
// Batched via blockIdx.z: off = (z/ZD)*Hi + (z%ZD)*Lo (element offsets).
template <int BN, int BIAS, int RELU, int EXPE, int RSCALE, int SB16, int SF32>
__global__ __launch_bounds__(256) void gemm_k(
    const u16* __restrict__ Ab, long aHi, long aLo, int lda,
    const u16* __restrict__ Bt, long bHi, long bLo, int ldb,
    float* __restrict__ Cf, u16* __restrict__ Cb,
    long cHi, long cLo, int ldc,
    const float* __restrict__ bias, const float* __restrict__ rs,
    int K, int ZD) {
  constexpr int NT = BN / 32;               // n-tiles per wave
  constexpr int CB = (BN * 64 * 2) / 1024;  // B-tile 1KB chunks
  __shared__ __align__(128) u16 As[128 * 64];
  __shared__ __align__(128) u16 Bs[BN * 64];

  const int tid = threadIdx.x;
  const int lane = tid & 63;
  const int wave = tid >> 6;
  const int waveM = wave >> 1, waveN = wave & 1;
  const int quad = lane >> 4, l16 = lane & 15;

  const int zb = blockIdx.z / ZD, zr = blockIdx.z % ZD;
  const long aOff = zb * aHi + zr * aLo;
  const long bOff = zb * bHi + zr * bLo;
  const long cOff = zb * cHi + zr * cLo;

  const int row0 = blockIdx.y * 128;
  const int col0 = blockIdx.x * BN;

  const int lr = lane >> 3;       // row within 8-row chunk
  const int lc = (lane & 7) * 8;  // col (elems)

  f32x4 acc[4][NT] = {};

  for (int k0 = 0; k0 < K; k0 += 64) {
    const u16* Ag = Ab + aOff + (long)row0 * lda + k0;
    const u16* Bg = Bt + bOff + (long)col0 * ldb + k0;
    // stage A: 128x64 bf16 = 16 chunks of 1KB, 4 per wave
#pragma unroll
    for (int c = 0; c < 4; ++c) {
      int ch = c * 4 + wave;
      gload16(Ag + (long)(ch * 8 + lr) * lda + lc, &As[ch * 512]);
    }
    // stage Bt: BN x 64 bf16
#pragma unroll
    for (int c = 0; c < CB / 4; ++c) {
      int ch = c * 4 + wave;
      gload16(Bg + (long)(ch * 8 + lr) * ldb + lc, &Bs[ch * 512]);
    }
    __syncthreads();  // drains vmcnt

    bf16x8 af[4][2], bfr[NT][2];
#pragma unroll
    for (int mi = 0; mi < 4; ++mi)
#pragma unroll
      for (int ks = 0; ks < 2; ++ks)
        af[mi][ks] = *(const bf16x8*)&As[(waveM * 64 + mi * 16 + l16) * 64 + ks * 32 + quad * 8];
#pragma unroll
    for (int ni = 0; ni < NT; ++ni)
#pragma unroll
      for (int ks = 0; ks < 2; ++ks)
        bfr[ni][ks] = *(const bf16x8*)&Bs[(waveN * (BN / 2) + ni * 16 + l16) * 64 + ks * 32 + quad * 8];
#pragma unroll
    for (int ks = 0; ks < 2; ++ks)
#pragma unroll
      for (int mi = 0; mi < 4; ++mi)
#pragma unroll
        for (int ni = 0; ni < NT; ++ni)
          acc[mi][ni] = __builtin_amdgcn_mfma_f32_16x16x32_bf16(af[mi][ks], bfr[ni][ks], acc[mi][ni], 0, 0, 0);
    __syncthreads();
  }

  // epilogue: D[row=quad*4+r][col=l16] per 16x16 tile
#pragma unroll
  for (int ni = 0; ni < NT; ++ni) {
    int col = col0 + waveN * (BN / 2) + ni * 16 + l16;
    float bv = BIAS ? bias[col] : 0.f;
#pragma unroll
    for (int mi = 0; mi < 4; ++mi) {
#pragma unroll
      for (int r = 0; r < 4; ++r) {
        int row = row0 + waveM * 64 + mi * 16 + quad * 4 + r;
        float v = acc[mi][ni][r] + bv;
        if (RELU) v = fmaxf(v, 0.f);
        if (EXPE) v = __expf(v * 0.125f);  // exp(score/8), no max-sub (|s/8| < ~3)
        if (RSCALE) v *= rs[(long)blockIdx.z * 1024 + row];
        long idx = cOff + (long)row * ldc + col;
        if (SF32) Cf[idx] = v;
        if (SB16) Cb[idx] = f2b(v);
      }
    }
  }
}

// ---------------- normalize: read unnormalized exp row (bf16), write fp32 weights + 1/sum
__global__ __launch_bounds__(256) void norm_k(const u16* __restrict__ e,
                                              float* __restrict__ w,
                                              float* __restrict__ inv) {
  long row = blockIdx.x;
  int tid = threadIdx.x;
  ushort4 ev = *(const ushort4*)(e + row * 1024 + tid * 4);
  float4 v;
  v.x = b2f(ev.x); v.y = b2f(ev.y); v.z = b2f(ev.z); v.w = b2f(ev.w);
  float s = v.x + v.y + v.z + v.w;
#pragma unroll
  for (int d = 32; d > 0; d >>= 1) s += __shfl_xor(s, d);
  __shared__ float red[4];
  if ((tid & 63) == 0) red[tid >> 6] = s;
  __syncthreads();
  s = red[0] + red[1] + red[2] + red[3];
  float r = 1.f / s;
  float4 o = make_float4(v.x * r, v.y * r, v.z * r, v.w * r);
  *(float4*)(w + row * 1024 + tid * 4) = o;
  if (tid == 0) inv[row] = r;
}

// ---------------- fused residual add + layernorm, row of 1024 ----------------
template <int WB16>
__global__ __launch_bounds__(256) void add_ln_k(const float* __restrict__ xp,
                                                const float* __restrict__ yp,
                                                const float* __restrict__ g,
                                                const float* __restrict__ bta,
                                                float* __restrict__ of,
                                                u16* __restrict__ ob) {
  long row = blockIdx.x;
  int tid = threadIdx.x;
  const float4 xv = *(const float4*)(xp + row * 1024 + tid * 4);
  const float4 yv = *(const float4*)(yp + row * 1024 + tid * 4);
  float4 v = make_float4(xv.x + yv.x, xv.y + yv.y, xv.z + yv.z, xv.w + yv.w);
  float s1 = v.x + v.y + v.z + v.w;
  float s2 = v.x * v.x + v.y * v.y + v.z * v.z + v.w * v.w;
#pragma unroll
  for (int d = 32; d > 0; d >>= 1) {
    s1 += __shfl_xor(s1, d);
    s2 += __shfl_xor(s2, d);
  }
  __shared__ float r1[4], r2[4];
  if ((tid & 63) == 0) { r1[tid >> 6] = s1; r2[tid >> 6] = s2; }
  __syncthreads();
  s1 = r1[0] + r1[1] + r1[2] + r1[3];
  s2 = r2[0] + r2[1] + r2[2] + r2[3];
  float mu = s1 * (1.f / 1024.f);
  float var = s2 * (1.f / 1024.f) - mu * mu;
  float rs = rsqrtf(var + 1e-5f);
  float4 gv = *(const float4*)(g + tid * 4);
  float4 bv = *(const float4*)(bta + tid * 4);
  float4 o;
  o.x = (v.x - mu) * rs * gv.x + bv.x;
  o.y = (v.y - mu) * rs * gv.y + bv.y;
  o.z = (v.z - mu) * rs * gv.z + bv.z;
  o.w = (v.w - mu) * rs * gv.w + bv.w;
  *(float4*)(of + row * 1024 + tid * 4) = o;
  if (WB16) {
    ushort4 ov = make_ushort4(f2b(o.x), f2b(o.y), f2b(o.z), f2b(o.w));
    *(ushort4*)(ob + row * 1024 + tid * 4) = ov;
  }
}

extern "C" void kernel_launch(void* const* d_in, const int* in_sizes, int n_in,
                              void* d_out, int out_size, void* d_ws, size_t ws_size,
                              hipStream_t stream) {
  const float* x   = (const float*)d_in[0];
  const float* Wq  = (const float*)d_in[1];
  const float* bq  = (const float*)d_in[2];
  const float* Wk  = (const float*)d_in[3];
  const float* bk  = (const float*)d_in[4];
  const float* Wv  = (const float*)d_in[5];
  const float* bv  = (const float*)d_in[6];
  const float* Wo  = (const float*)d_in[7];
  const float* bo  = (const float*)d_in[8];
  const float* W1  = (const float*)d_in[9];
  const float* b1  = (const float*)d_in[10];
  const float* W2  = (const float*)d_in[11];
  const float* b2  = (const float*)d_in[12];
  const float* g1  = (const float*)d_in[13];
  const float* be1 = (const float*)d_in[14];
  const float* g2  = (const float*)d_in[15];
  const float* be2 = (const float*)d_in[16];

  float* out = (float*)d_out;
  float* attn = out + 4194304LL;  // [4,16,1024,1024] fp32 (post-softmax weights)

  char* w = (char*)d_ws;
  size_t off = 0;
  auto alloc = [&](size_t bytes) {
    void* p = w + off;
    off = (off + bytes + 255) & ~(size_t)255;
    return p;
  };
  u16* xb        = (u16*)alloc(8388608);     // x bf16 [4096,1024]
  u16* Wqkvt     = (u16*)alloc(6291456);     // [3072,1024] bf16 (Wq^T|Wk^T|Wv^T)
  u16* Wot       = (u16*)alloc(2097152);     // [1024,1024]
  u16* W1t       = (u16*)alloc(8388608);     // [4096,1024]
  u16* W2t       = (u16*)alloc(8388608);     // [1024,4096]
  float* bqkv    = (float*)alloc(12288);     // [3072]
  u16* qkvb      = (u16*)alloc(25165824);    // [4096,3072] bf16
  u16* vtb       = (u16*)alloc(8388608);     // [64,64,1024] bf16
  u16* expb      = (u16*)alloc(134217728);   // [64,1024,1024] bf16 unnormalized exp
  float* inv     = (float*)alloc(262144);    // [65536] 1/rowsum
  u16* ctxb      = (u16*)alloc(8388608);     // [4096,1024] bf16
  float* attn_o  = (float*)alloc(16777216);  // [4096,1024] fp32
  float* x1      = (float*)alloc(16777216);  // post-LN1 fp32
  u16* x1b       = (u16*)alloc(8388608);
  u16* ff1b      = (u16*)alloc(33554432);    // [4096,4096] bf16
  float* ff2     = (float*)alloc(16777216);
  (void)ws_size; (void)in_sizes; (void)n_in; (void)out_size;

  dim3 tb(32, 8);
  // pack inputs to bf16 / transposed-bf16
  cast_k<<<4096, 256, 0, stream>>>(x, xb, 1048576);
  transpose_k<<<dim3(32, 32), tb, 0, stream>>>(Wq, Wqkvt,           1024, 1024);
  transpose_k<<<dim3(32, 32), tb, 0, stream>>>(Wk, Wqkvt + 1048576, 1024, 1024);
  transpose_k<<<dim3(32, 32), tb, 0, stream>>>(Wv, Wqkvt + 2097152, 1024, 1024);
  transpose_k<<<dim3(32, 32), tb, 0, stream>>>(Wo, Wot, 1024, 1024);
  transpose_k<<<dim3(128, 32), tb, 0, stream>>>(W1, W1t, 4096, 1024);
  transpose_k<<<dim3(32, 128), tb, 0, stream>>>(W2, W2t, 1024, 4096);
  hipMemcpyAsync(bqkv,        bq, 4096, hipMemcpyDeviceToDevice, stream);
  hipMemcpyAsync(bqkv + 1024, bk, 4096, hipMemcpyDeviceToDevice, stream);
  hipMemcpyAsync(bqkv + 2048, bv, 4096, hipMemcpyDeviceToDevice, stream);

  // QKV projection: [4096,1024]x[1024,3072] -> qkvb bf16
  gemm_k<128, 1, 0, 0, 0, 1, 0><<<dim3(24, 32, 1), 256, 0, stream>>>(
      xb, 0, 0, 1024, Wqkvt, 0, 0, 1024,
      nullptr, qkvb, 0, 0, 3072, bqkv, nullptr, 1024, 1);

  transpose_v_k<<<dim3(32, 2, 64), tb, 0, stream>>>(qkvb, vtb);

  // scores+exp: per (b,h): exp(Q K^T / 8) -> expb bf16 (unnormalized)
  gemm_k<128, 0, 0, 1, 0, 1, 0><<<dim3(8, 8, 64), 256, 0, stream>>>(
      qkvb, 3145728L, 64, 3072,
      qkvb + 1024, 3145728L, 64, 3072,
      nullptr, expb, 16777216L, 1048576L, 1024, nullptr, nullptr, 64, 16);

  // rowsum + final fp32 attention weights + 1/sum
  norm_k<<<65536, 256, 0, stream>>>(expb, attn, inv);

  // ctx: per (b,h): expb[1024,1024] x V[1024,64], scaled by 1/rowsum -> ctxb bf16
  gemm_k<64, 0, 0, 0, 1, 1, 0><<<dim3(1, 8, 64), 256, 0, stream>>>(
      expb, 16777216L, 1048576L, 1024,
      vtb, 1048576L, 65536L, 1024,
      nullptr, ctxb, 1048576L, 64, 1024, nullptr, inv, 1024, 16);

  // attn_out = ctx x Wo + bo (fp32)
  gemm_k<128, 1, 0, 0, 0, 0, 1><<<dim3(8, 32, 1), 256, 0, stream>>>(
      ctxb, 0, 0, 1024, Wot, 0, 0, 1024,
      attn_o, nullptr, 0, 0, 1024, bo, nullptr, 1024, 1);

  // x1 = LN(x + attn_out)
  add_ln_k<1><<<4096, 256, 0, stream>>>(x, attn_o, g1, be1, x1, x1b);

  // ff1 = relu(x1 W1 + b1) -> bf16
  gemm_k<128, 1, 1, 0, 0, 1, 0><<<dim3(32, 32, 1), 256, 0, stream>>>(
      x1b, 0, 0, 1024, W1t, 0, 0, 1024,
      nullptr, ff1b, 0, 0, 4096, b1, nullptr, 1024, 1);

  // ff2 = ff1 W2 + b2 (fp32)
  gemm_k<128, 1, 0, 0, 0, 0, 1><<<dim3(8, 32, 1), 256, 0, stream>>>(
      ff1b, 0, 0, 4096, W2t, 0, 0, 4096,
      ff2, nullptr, 0, 0, 1024, b2, nullptr, 4096, 1);

  // out = LN(x1 + ff2)
  add_ln_k<0><<<4096, 256, 0, stream>>>(x1, ff2, g2, be2, out, nullptr);
}

// Round 2
// 726.952 us; speedup vs baseline: 1.1317x; 1.0371x over previous
//
#include <hip/hip_runtime.h>

typedef unsigned short u16;
typedef __attribute__((ext_vector_type(8))) short bf16x8;
typedef __attribute__((ext_vector_type(4))) float f32x4;

__device__ __forceinline__ u16 f2b(float f) {
  unsigned u = __float_as_uint(f);
  u += 0x7fffu + ((u >> 16) & 1u);
  return (u16)(u >> 16);
}
__device__ __forceinline__ float b2f(u16 v) {
  return __uint_as_float((unsigned)v << 16);
}

// async global -> LDS, 16B per lane. LDS dest wave-uniform base; HW adds lane*16.
__device__ __forceinline__ void gload16(const u16* g, u16* l) {
  __builtin_amdgcn_global_load_lds((__attribute__((address_space(1))) void*)(g),
                                   (__attribute__((address_space(3))) void*)(l), 16, 0, 0);
}

// ---------------- cast fp32 -> bf16 (vectorized) ----------------
__global__ __launch_bounds__(256) void cast_k(const float* __restrict__ s,
                                              u16* __restrict__ d, int n4) {
  int i = blockIdx.x * 256 + threadIdx.x;
  if (i >= n4) return;
  float4 v = *(const float4*)(s + (size_t)i * 4);
  ushort4 o = make_ushort4(f2b(v.x), f2b(v.y), f2b(v.z), f2b(v.w));
  *(ushort4*)(d + (size_t)i * 4) = o;
}

// ---------------- fp32 [R x C] -> bf16 transposed [C x R] ----------------
__global__ __launch_bounds__(256) void transpose_k(const float* __restrict__ src,
                                                   u16* __restrict__ dst,
                                                   int ldsrc, int lddst) {
  __shared__ float t[32][33];
  int c0 = blockIdx.x * 32, r0 = blockIdx.y * 32;
  int tx = threadIdx.x, ty = threadIdx.y;
#pragma unroll
  for (int i = 0; i < 4; ++i)
    t[ty + i * 8][tx] = src[(size_t)(r0 + ty + i * 8) * ldsrc + c0 + tx];
  __syncthreads();
#pragma unroll
  for (int i = 0; i < 4; ++i)
    dst[(size_t)(c0 + ty + i * 8) * lddst + r0 + tx] = f2b(t[tx][ty + i * 8]);
}

// ---------------- 4x 1024x1024 fp32 -> bf16 transpose in one launch ----------------
__global__ __launch_bounds__(256) void transpose4_k(const float* __restrict__ Wq,
                                                    const float* __restrict__ Wk,
                                                    const float* __restrict__ Wv,
                                                    const float* __restrict__ Wo,
                                                    u16* __restrict__ Wqkvt,
                                                    u16* __restrict__ Wot) {
  __shared__ float t[32][33];
  int z = blockIdx.z;
  const float* src = z == 0 ? Wq : z == 1 ? Wk : z == 2 ? Wv : Wo;
  u16* dst = z < 3 ? Wqkvt + (size_t)z * 1048576 : Wot;
  int c0 = blockIdx.x * 32, r0 = blockIdx.y * 32;
  int tx = threadIdx.x, ty = threadIdx.y;
#pragma unroll
  for (int i = 0; i < 4; ++i)
    t[ty + i * 8][tx] = src[(size_t)(r0 + ty + i * 8) * 1024 + c0 + tx];
  __syncthreads();
#pragma unroll
  for (int i = 0; i < 4; ++i)
    dst[(size_t)(c0 + ty + i * 8) * 1024 + r0 + tx] = f2b(t[tx][ty + i * 8]);
}

// ---------------- V head-transpose: qkv[(b*S+s)*3072 + 2048 + h*64 + d] -> vt[bh][d][s]
__global__ __launch_bounds__(256) void transpose_v_k(const u16* __restrict__ qkv,
                                                     u16* __restrict__ vt) {
  __shared__ u16 t[32][33];
  int z = blockIdx.z;
  int b = z >> 4, h = z & 15;
  int s0 = blockIdx.x * 32, d0 = blockIdx.y * 32;
  int tx = threadIdx.x, ty = threadIdx.y;
  const u16* src = qkv + (size_t)(b * 1024) * 3072 + 2048 + h * 64;
  u16* dst = vt + (size_t)z * 65536;
#pragma unroll
  for (int i = 0; i < 4; ++i)
    t[ty + i * 8][tx] = src[(size_t)(s0 + ty + i * 8) * 3072 + d0 + tx];
  __syncthreads();
#pragma unroll
  for (int i = 0; i < 4; ++i)
    dst[(size_t)(d0 + i * 8 + ty) * 1024 + s0 + tx] = t[tx][ty + i * 8];
}

// ---------------- GEMM: C[M,N] = A[M,K] * Bt[N,K]^T  (m97 structure)
// Block 256 thr = 4 waves (2x2), tile 128 x BN, BK=64, global_load_lds staging,
// linear LDS [rows][64]. MFMA 16x16x32 bf16.
// BIAS: 0 none, 1 single ptr, 3 = concat(bq|bk|bv). RESID: add resid[idx] (residual fuse).
template <int BN, int BIAS, int RELU, int SB16, int SF32, int RESID>
__global__ __launch_bounds__(256) void gemm_k(
    const u16* __restrict__ Ab, long aHi, long aLo, int lda,
    const u16* __restrict__ Bt, long bHi, long bLo, int ldb,
    float* __restrict__ Cf, u16* __restrict__ Cb,
    long cHi, long cLo, int ldc,
    const float* __restrict__ bias, const float* __restrict__ biasB,
    const float* __restrict__ biasC, const float* __restrict__ resid,
    int K, int ZD) {
  constexpr int NT = BN / 32;               // n-tiles per wave
  constexpr int CB = (BN * 64 * 2) / 1024;  // B-tile 1KB chunks
  __shared__ __align__(128) u16 As[128 * 64];
  __shared__ __align__(128) u16 Bs[BN * 64];

  const int tid = threadIdx.x;
  const int lane = tid & 63;
  const int wave = tid >> 6;
  const int waveM = wave >> 1, waveN = wave & 1;
  const int quad = lane >> 4, l16 = lane & 15;

  const int zb = blockIdx.z / ZD, zr = blockIdx.z % ZD;
  const long aOff = zb * aHi + zr * aLo;
  const long bOff = zb * bHi + zr * bLo;
  const long cOff = zb * cHi + zr * cLo;

  const int row0 = blockIdx.y * 128;
  const int col0 = blockIdx.x * BN;

  const int lr = lane >> 3;       // row within 8-row chunk
  const int lc = (lane & 7) * 8;  // col (elems)

  f32x4 acc[4][NT] = {};

  for (int k0 = 0; k0 < K; k0 += 64) {
    const u16* Ag = Ab + aOff + (long)row0 * lda + k0;
    const u16* Bg = Bt + bOff + (long)col0 * ldb + k0;
#pragma unroll
    for (int c = 0; c < 4; ++c) {
      int ch = c * 4 + wave;
      gload16(Ag + (long)(ch * 8 + lr) * lda + lc, &As[ch * 512]);
    }
#pragma unroll
    for (int c = 0; c < CB / 4; ++c) {
      int ch = c * 4 + wave;
      gload16(Bg + (long)(ch * 8 + lr) * ldb + lc, &Bs[ch * 512]);
    }
    __syncthreads();  // drains vmcnt

    bf16x8 af[4][2], bfr[NT][2];
#pragma unroll
    for (int mi = 0; mi < 4; ++mi)
#pragma unroll
      for (int ks = 0; ks < 2; ++ks)
        af[mi][ks] = *(const bf16x8*)&As[(waveM * 64 + mi * 16 + l16) * 64 + ks * 32 + quad * 8];
#pragma unroll
    for (int ni = 0; ni < NT; ++ni)
#pragma unroll
      for (int ks = 0; ks < 2; ++ks)
        bfr[ni][ks] = *(const bf16x8*)&Bs[(waveN * (BN / 2) + ni * 16 + l16) * 64 + ks * 32 + quad * 8];
#pragma unroll
    for (int ks = 0; ks < 2; ++ks)
#pragma unroll
      for (int mi = 0; mi < 4; ++mi)
#pragma unroll
        for (int ni = 0; ni < NT; ++ni)
          acc[mi][ni] = __builtin_amdgcn_mfma_f32_16x16x32_bf16(af[mi][ks], bfr[ni][ks], acc[mi][ni], 0, 0, 0);
    __syncthreads();
  }

  // epilogue: D[row=quad*4+r][col=l16] per 16x16 tile
#pragma unroll
  for (int ni = 0; ni < NT; ++ni) {
    int col = col0 + waveN * (BN / 2) + ni * 16 + l16;
    float bv = 0.f;
    if (BIAS == 1) bv = bias[col];
    if (BIAS == 3) bv = col < 1024 ? bias[col] : (col < 2048 ? biasB[col - 1024] : biasC[col - 2048]);
#pragma unroll
    for (int mi = 0; mi < 4; ++mi) {
#pragma unroll
      for (int r = 0; r < 4; ++r) {
        int row = row0 + waveM * 64 + mi * 16 + quad * 4 + r;
        float v = acc[mi][ni][r] + bv;
        if (RELU) v = fmaxf(v, 0.f);
        long idx = cOff + (long)row * ldc + col;
        if (RESID) v += resid[idx];
        if (SF32) Cf[idx] = v;
        if (SB16) Cb[idx] = f2b(v);
      }
    }
  }
}

// ---------------- fused scores + softmax: per (b,h), 64 q-rows/block, full 1024 cols.
// QK^T (K=64, one k-step) -> exp(s/8) kept packed bf16 in regs -> rowsum via 16-lane
// butterfly -> write normalized fp32 attn + normalized bf16 expb (for ctx GEMM).
__global__ __launch_bounds__(256) void score_softmax_k(const u16* __restrict__ qkvb,
                                                       float* __restrict__ attn,
                                                       u16* __restrict__ expb) {
  __shared__ __align__(128) u16 Bs[256 * 64];  // K-chunk: 256 rows x 64 (32KB)
  const int tid = threadIdx.x;
  const int lane = tid & 63;
  const int w = tid >> 6;
  const int quad = lane >> 4, l16 = lane & 15;
  const int lr = lane >> 3, lc = (lane & 7) * 8;

  const int z = blockIdx.y;          // b*16+h
  const int b = z >> 4, h = z & 15;
  const u16* Q  = qkvb + (long)b * 3145728 + h * 64;
  const u16* Kt = qkvb + (long)b * 3145728 + 1024 + h * 64;

  const int qrow = blockIdx.x * 64 + w * 16 + l16;  // A-frag row
  bf16x8 af[2];
  af[0] = *(const bf16x8*)&Q[(long)qrow * 3072 + quad * 8];
  af[1] = *(const bf16x8*)&Q[(long)qrow * 3072 + 32 + quad * 8];

  unsigned p[4][32];      // packed unnormalized exp, [chunk][ni*2 + half]
  float rowpart[4] = {0.f, 0.f, 0.f, 0.f};

#pragma unroll 4
  for (int nc = 0; nc < 4; ++nc) {
    // stage K rows [nc*256, nc*256+256) x 64 cols
#pragma unroll
    for (int c = 0; c < 8; ++c) {
      int ch = c * 4 + w;
      gload16(Kt + (long)(nc * 256 + ch * 8 + lr) * 3072 + lc, &Bs[ch * 512]);
    }
    __syncthreads();
#pragma unroll
    for (int ni = 0; ni < 16; ++ni) {
      bf16x8 b0 = *(const bf16x8*)&Bs[(ni * 16 + l16) * 64 + quad * 8];
      bf16x8 b1 = *(const bf16x8*)&Bs[(ni * 16 + l16) * 64 + 32 + quad * 8];
      f32x4 acc = {};
      acc = __builtin_amdgcn_mfma_f32_16x16x32_bf16(af[0], b0, acc, 0, 0, 0);
      acc = __builtin_amdgcn_mfma_f32_16x16x32_bf16(af[1], b1, acc, 0, 0, 0);
      float e0 = __expf(acc[0] * 0.125f);
      float e1 = __expf(acc[1] * 0.125f);
      float e2 = __expf(acc[2] * 0.125f);
      float e3 = __expf(acc[3] * 0.125f);
      rowpart[0] += e0; rowpart[1] += e1; rowpart[2] += e2; rowpart[3] += e3;
      p[nc][ni * 2]     = (unsigned)f2b(e0) | ((unsigned)f2b(e1) << 16);
      p[nc][ni * 2 + 1] = (unsigned)f2b(e2) | ((unsigned)f2b(e3) << 16);
    }
    __syncthreads();
  }

  // rowsum over the 16 l16 lanes (rows are owned per (w,quad,r))
#pragma unroll
  for (int d = 1; d < 16; d <<= 1) {
#pragma unroll
    for (int r = 0; r < 4; ++r) rowpart[r] += __shfl_xor(rowpart[r], d);
  }
  float inv0 = 1.f / rowpart[0], inv1 = 1.f / rowpart[1];
  float inv2 = 1.f / rowpart[2], inv3 = 1.f / rowpart[3];

  const long rbase = (long)z * 1048576 + (long)(blockIdx.x * 64 + w * 16 + quad * 4) * 1024;
#pragma unroll 4
  for (int nc = 0; nc < 4; ++nc) {
#pragma unroll
    for (int ni = 0; ni < 16; ++ni) {
      int col = nc * 256 + ni * 16 + l16;
      unsigned w0 = p[nc][ni * 2], w1 = p[nc][ni * 2 + 1];
      float e0 = b2f((u16)(w0 & 0xffff)) * inv0;
      float e1 = b2f((u16)(w0 >> 16)) * inv1;
      float e2 = b2f((u16)(w1 & 0xffff)) * inv2;
      float e3 = b2f((u16)(w1 >> 16)) * inv3;
      attn[rbase + col] = e0;
      attn[rbase + 1024 + col] = e1;
      attn[rbase + 2048 + col] = e2;
      attn[rbase + 3072 + col] = e3;
      expb[rbase + col] = f2b(e0);
      expb[rbase + 1024 + col] = f2b(e1);
      expb[rbase + 2048 + col] = f2b(e2);
      expb[rbase + 3072 + col] = f2b(e3);
    }
  }
}

// ---------------- residual(+)/layernorm, row of 1024 ----------------
template <int WB16, int ADD>
__global__ __launch_bounds__(256) void add_ln_k(const float* __restrict__ xp,
                                                const float* __restrict__ yp,
                                                const float* __restrict__ g,
                                                const float* __restrict__ bta,
                                                float* __restrict__ of,
                                                u16* __restrict__ ob) {
  long row = blockIdx.x;
  int tid = threadIdx.x;
  float4 v = *(const float4*)(xp + row * 1024 + tid * 4);
  if (ADD) {
    const float4 yv = *(const float4*)(yp + row * 1024 + tid * 4);
    v.x += yv.x; v.y += yv.y; v.z += yv.z; v.w += yv.w;
  }
  float s1 = v.x + v.y + v.z + v.w;
  float s2 = v.x * v.x + v.y * v.y + v.z * v.z + v.w * v.w;
#pragma unroll
  for (int d = 32; d > 0; d >>= 1) {
    s1 += __shfl_xor(s1, d);
    s2 += __shfl_xor(s2, d);
  }
  __shared__ float r1[4], r2[4];
  if ((tid & 63) == 0) { r1[tid >> 6] = s1; r2[tid >> 6] = s2; }
  __syncthreads();
  s1 = r1[0] + r1[1] + r1[2] + r1[3];
  s2 = r2[0] + r2[1] + r2[2] + r2[3];
  float mu = s1 * (1.f / 1024.f);
  float var = s2 * (1.f / 1024.f) - mu * mu;
  float rs = rsqrtf(var + 1e-5f);
  float4 gv = *(const float4*)(g + tid * 4);
  float4 bv = *(const float4*)(bta + tid * 4);
  float4 o;
  o.x = (v.x - mu) * rs * gv.x + bv.x;
  o.y = (v.y - mu) * rs * gv.y + bv.y;
  o.z = (v.z - mu) * rs * gv.z + bv.z;
  o.w = (v.w - mu) * rs * gv.w + bv.w;
  *(float4*)(of + row * 1024 + tid * 4) = o;
  if (WB16) {
    ushort4 ov = make_ushort4(f2b(o.x), f2b(o.y), f2b(o.z), f2b(o.w));
    *(ushort4*)(ob + row * 1024 + tid * 4) = ov;
  }
}

extern "C" void kernel_launch(void* const* d_in, const int* in_sizes, int n_in,
                              void* d_out, int out_size, void* d_ws, size_t ws_size,
                              hipStream_t stream) {
  const float* x   = (const float*)d_in[0];
  const float* Wq  = (const float*)d_in[1];
  const float* bq  = (const float*)d_in[2];
  const float* Wk  = (const float*)d_in[3];
  const float* bk  = (const float*)d_in[4];
  const float* Wv  = (const float*)d_in[5];
  const float* bv  = (const float*)d_in[6];
  const float* Wo  = (const float*)d_in[7];
  const float* bo  = (const float*)d_in[8];
  const float* W1  = (const float*)d_in[9];
  const float* b1  = (const float*)d_in[10];
  const float* W2  = (const float*)d_in[11];
  const float* b2  = (const float*)d_in[12];
  const float* g1  = (const float*)d_in[13];
  const float* be1 = (const float*)d_in[14];
  const float* g2  = (const float*)d_in[15];
  const float* be2 = (const float*)d_in[16];

  float* out = (float*)d_out;
  float* attn = out + 4194304LL;  // [4,16,1024,1024] fp32 (post-softmax weights)

  char* w = (char*)d_ws;
  size_t off = 0;
  auto alloc = [&](size_t bytes) {
    void* p = w + off;
    off = (off + bytes + 255) & ~(size_t)255;
    return p;
  };
  u16* xb        = (u16*)alloc(8388608);     // x bf16 [4096,1024]
  u16* Wqkvt     = (u16*)alloc(6291456);     // [3072,1024] bf16 (Wq^T|Wk^T|Wv^T)
  u16* Wot       = (u16*)alloc(2097152);     // [1024,1024]
  u16* W1t       = (u16*)alloc(8388608);     // [4096,1024]
  u16* W2t       = (u16*)alloc(8388608);     // [1024,4096]
  u16* qkvb      = (u16*)alloc(25165824);    // [4096,3072] bf16
  u16* vtb       = (u16*)alloc(8388608);     // [64,64,1024] bf16
  u16* expb      = (u16*)alloc(134217728);   // [64,1024,1024] bf16 normalized weights
  u16* ctxb      = (u16*)alloc(8388608);     // [4096,1024] bf16
  float* attn_o  = (float*)alloc(16777216);  // [4096,1024] fp32 (= ctx Wo + bo + x)
  float* x1      = (float*)alloc(16777216);  // post-LN1 fp32
  u16* x1b       = (u16*)alloc(8388608);
  u16* ff1b      = (u16*)alloc(33554432);    // [4096,4096] bf16
  float* ff2     = (float*)alloc(16777216);  // (= ff1 W2 + b2 + x1)
  (void)ws_size; (void)in_sizes; (void)n_in; (void)out_size;

  dim3 tb(32, 8);
  // pack inputs to bf16 / transposed-bf16
  cast_k<<<4096, 256, 0, stream>>>(x, xb, 1048576);
  transpose4_k<<<dim3(32, 32, 4), tb, 0, stream>>>(Wq, Wk, Wv, Wo, Wqkvt, Wot);
  transpose_k<<<dim3(128, 32), tb, 0, stream>>>(W1, W1t, 4096, 1024);
  transpose_k<<<dim3(32, 128), tb, 0, stream>>>(W2, W2t, 1024, 4096);

  // QKV projection: [4096,1024]x[1024,3072] -> qkvb bf16 (bias = bq|bk|bv concat)
  gemm_k<128, 3, 0, 1, 0, 0><<<dim3(24, 32, 1), 256, 0, stream>>>(
      xb, 0, 0, 1024, Wqkvt, 0, 0, 1024,
      nullptr, qkvb, 0, 0, 3072, bq, bk, bv, nullptr, 1024, 1);

  transpose_v_k<<<dim3(32, 2, 64), tb, 0, stream>>>(qkvb, vtb);

  // fused scores + softmax -> attn fp32 + expb bf16 (both normalized)
  score_softmax_k<<<dim3(16, 64), 256, 0, stream>>>(qkvb, attn, expb);

  // ctx: per (b,h): attn_bf16[1024,1024] x V[1024,64] -> ctxb bf16 [4096,1024]
  gemm_k<64, 0, 0, 1, 0, 0><<<dim3(1, 8, 64), 256, 0, stream>>>(
      expb, 16777216L, 1048576L, 1024,
      vtb, 1048576L, 65536L, 1024,
      nullptr, ctxb, 1048576L, 64, 1024, nullptr, nullptr, nullptr, nullptr, 1024, 16);

  // attn_o = ctx x Wo + bo + x (residual fused)
  gemm_k<64, 1, 0, 0, 1, 1><<<dim3(16, 32, 1), 256, 0, stream>>>(
      ctxb, 0, 0, 1024, Wot, 0, 0, 1024,
      attn_o, nullptr, 0, 0, 1024, bo, nullptr, nullptr, x, 1024, 1);

  // x1 = LN(attn_o)
  add_ln_k<1, 0><<<4096, 256, 0, stream>>>(attn_o, nullptr, g1, be1, x1, x1b);

  // ff1 = relu(x1 W1 + b1) -> bf16
  gemm_k<128, 1, 1, 1, 0, 0><<<dim3(32, 32, 1), 256, 0, stream>>>(
      x1b, 0, 0, 1024, W1t, 0, 0, 1024,
      nullptr, ff1b, 0, 0, 4096, b1, nullptr, nullptr, nullptr, 1024, 1);

  // ff2 = ff1 W2 + b2 + x1 (residual fused)
  gemm_k<64, 1, 0, 0, 1, 1><<<dim3(16, 32, 1), 256, 0, stream>>>(
      ff1b, 0, 0, 4096, W2t, 0, 0, 4096,
      ff2, nullptr, 0, 0, 1024, b2, nullptr, nullptr, x1, 4096, 1);

  // out = LN(ff2)
  add_ln_k<0, 0><<<4096, 256, 0, stream>>>(ff2, nullptr, g2, be2, out, nullptr);
}

// Round 4
// 699.863 us; speedup vs baseline: 1.1755x; 1.0387x over previous
//
#include <hip/hip_runtime.h>

typedef unsigned short u16;
typedef __attribute__((ext_vector_type(8))) short bf16x8;
typedef __attribute__((ext_vector_type(4))) float f32x4;

__device__ __forceinline__ u16 f2b(float f) {
  unsigned u = __float_as_uint(f);
  u += 0x7fffu + ((u >> 16) & 1u);
  return (u16)(u >> 16);
}
__device__ __forceinline__ float b2f(u16 v) {
  return __uint_as_float((unsigned)v << 16);
}

// async global -> LDS, 16B per lane. LDS dest wave-uniform base; HW adds lane*16.
__device__ __forceinline__ void gload16(const u16* g, u16* l) {
  __builtin_amdgcn_global_load_lds((__attribute__((address_space(1))) void*)(g),
                                   (__attribute__((address_space(3))) void*)(l), 16, 0, 0);
}

// ---------------- merged prep: cast x->bf16 + all weight transposes ----------------
// grid 16384: [0,4096) cast x; [4096,8192) Wq/Wk/Wv/Wo; [8192,12288) W1; [12288,16384) W2
__global__ __launch_bounds__(256) void prep_k(const float* __restrict__ x, u16* __restrict__ xb,
                                              const float* __restrict__ Wq, const float* __restrict__ Wk,
                                              const float* __restrict__ Wv, const float* __restrict__ Wo,
                                              const float* __restrict__ W1, const float* __restrict__ W2,
                                              u16* __restrict__ Wqkvt, u16* __restrict__ Wot,
                                              u16* __restrict__ W1t, u16* __restrict__ W2t) {
  int bid = blockIdx.x;
  if (bid < 4096) {
    int i = bid * 256 + threadIdx.x;
    float4 v = *(const float4*)(x + (size_t)i * 4);
    ushort4 o = make_ushort4(f2b(v.x), f2b(v.y), f2b(v.z), f2b(v.w));
    *(ushort4*)(xb + (size_t)i * 4) = o;
    return;
  }
  __shared__ float t[32][33];
  int tx = threadIdx.x & 31, ty = threadIdx.x >> 5;
  const float* src;
  u16* dst;
  int bx, by, ldsrc, lddst;
  int r = bid - 4096;
  if (r < 4096) {
    int which = r >> 10, rr = r & 1023;
    bx = rr & 31; by = rr >> 5; ldsrc = 1024; lddst = 1024;
    src = which == 0 ? Wq : which == 1 ? Wk : which == 2 ? Wv : Wo;
    dst = which < 3 ? Wqkvt + (size_t)which * 1048576 : Wot;
  } else if (r < 8192) {
    int rr = r - 4096;
    bx = rr & 127; by = rr >> 7; src = W1; dst = W1t; ldsrc = 4096; lddst = 1024;
  } else {
    int rr = r - 8192;
    bx = rr & 31; by = rr >> 5; src = W2; dst = W2t; ldsrc = 1024; lddst = 4096;
  }
  int c0 = bx * 32, r0 = by * 32;
#pragma unroll
  for (int i = 0; i < 4; ++i)
    t[ty + i * 8][tx] = src[(size_t)(r0 + ty + i * 8) * ldsrc + c0 + tx];
  __syncthreads();
#pragma unroll
  for (int i = 0; i < 4; ++i)
    dst[(size_t)(c0 + ty + i * 8) * lddst + r0 + tx] = f2b(t[tx][ty + i * 8]);
}

// ---------------- V head-transpose: qkv[(b*S+s)*3072 + 2048 + h*64 + d] -> vt[bh][d][s]
__global__ __launch_bounds__(256) void transpose_v_k(const u16* __restrict__ qkv,
                                                     u16* __restrict__ vt) {
  __shared__ u16 t[32][33];
  int z = blockIdx.z;
  int b = z >> 4, h = z & 15;
  int s0 = blockIdx.x * 32, d0 = blockIdx.y * 32;
  int tx = threadIdx.x, ty = threadIdx.y;
  const u16* src = qkv + (size_t)(b * 1024) * 3072 + 2048 + h * 64;
  u16* dst = vt + (size_t)z * 65536;
#pragma unroll
  for (int i = 0; i < 4; ++i)
    t[ty + i * 8][tx] = src[(size_t)(s0 + ty + i * 8) * 3072 + d0 + tx];
  __syncthreads();
#pragma unroll
  for (int i = 0; i < 4; ++i)
    dst[(size_t)(d0 + i * 8 + ty) * 1024 + s0 + tx] = t[tx][ty + i * 8];
}

// ---------------- GEMM: C[M,N] = A[M,K] * Bt[N,K]^T  (m97 structure) ----------------
template <int BN, int BIAS, int RELU, int SB16, int SF32, int RESID>
__global__ __launch_bounds__(256) void gemm_k(
    const u16* __restrict__ Ab, long aHi, long aLo, int lda,
    const u16* __restrict__ Bt, long bHi, long bLo, int ldb,
    float* __restrict__ Cf, u16* __restrict__ Cb,
    long cHi, long cLo, int ldc,
    const float* __restrict__ bias, const float* __restrict__ biasB,
    const float* __restrict__ biasC, const float* __restrict__ resid,
    int K, int ZD) {
  constexpr int NT = BN / 32;
  constexpr int CB = (BN * 64 * 2) / 1024;
  __shared__ __align__(128) u16 As[128 * 64];
  __shared__ __align__(128) u16 Bs[BN * 64];

  const int tid = threadIdx.x;
  const int lane = tid & 63;
  const int wave = tid >> 6;
  const int waveM = wave >> 1, waveN = wave & 1;
  const int quad = lane >> 4, l16 = lane & 15;

  const int zb = blockIdx.z / ZD, zr = blockIdx.z % ZD;
  const long aOff = zb * aHi + zr * aLo;
  const long bOff = zb * bHi + zr * bLo;
  const long cOff = zb * cHi + zr * cLo;

  const int row0 = blockIdx.y * 128;
  const int col0 = blockIdx.x * BN;

  const int lr = lane >> 3;
  const int lc = (lane & 7) * 8;

  f32x4 acc[4][NT] = {};

  for (int k0 = 0; k0 < K; k0 += 64) {
    const u16* Ag = Ab + aOff + (long)row0 * lda + k0;
    const u16* Bg = Bt + bOff + (long)col0 * ldb + k0;
#pragma unroll
    for (int c = 0; c < 4; ++c) {
      int ch = c * 4 + wave;
      gload16(Ag + (long)(ch * 8 + lr) * lda + lc, &As[ch * 512]);
    }
#pragma unroll
    for (int c = 0; c < CB / 4; ++c) {
      int ch = c * 4 + wave;
      gload16(Bg + (long)(ch * 8 + lr) * ldb + lc, &Bs[ch * 512]);
    }
    __syncthreads();

    bf16x8 af[4][2], bfr[NT][2];
#pragma unroll
    for (int mi = 0; mi < 4; ++mi)
#pragma unroll
      for (int ks = 0; ks < 2; ++ks)
        af[mi][ks] = *(const bf16x8*)&As[(waveM * 64 + mi * 16 + l16) * 64 + ks * 32 + quad * 8];
#pragma unroll
    for (int ni = 0; ni < NT; ++ni)
#pragma unroll
      for (int ks = 0; ks < 2; ++ks)
        bfr[ni][ks] = *(const bf16x8*)&Bs[(waveN * (BN / 2) + ni * 16 + l16) * 64 + ks * 32 + quad * 8];
#pragma unroll
    for (int ks = 0; ks < 2; ++ks)
#pragma unroll
      for (int mi = 0; mi < 4; ++mi)
#pragma unroll
        for (int ni = 0; ni < NT; ++ni)
          acc[mi][ni] = __builtin_amdgcn_mfma_f32_16x16x32_bf16(af[mi][ks], bfr[ni][ks], acc[mi][ni], 0, 0, 0);
    __syncthreads();
  }

#pragma unroll
  for (int ni = 0; ni < NT; ++ni) {
    int col = col0 + waveN * (BN / 2) + ni * 16 + l16;
    float bv = 0.f;
    if (BIAS == 1) bv = bias[col];
    if (BIAS == 3) bv = col < 1024 ? bias[col] : (col < 2048 ? biasB[col - 1024] : biasC[col - 2048]);
#pragma unroll
    for (int mi = 0; mi < 4; ++mi) {
#pragma unroll
      for (int r = 0; r < 4; ++r) {
        int row = row0 + waveM * 64 + mi * 16 + quad * 4 + r;
        float v = acc[mi][ni][r] + bv;
        if (RELU) v = fmaxf(v, 0.f);
        long idx = cOff + (long)row * ldc + col;
        if (RESID) v += resid[idx];
        if (SF32) Cf[idx] = v;
        if (SB16) Cb[idx] = f2b(v);
      }
    }
  }
}

// ---------------- fused attention: QK^T + softmax + PV + both outputs ----------------
// grid (16, 64): x = q-block (64 rows), y = b*16+h. 256 thr / 4 waves.
// Swapped QK^T: mfma(K,Q) -> C[k][q], lane owns q = w*16+l16, k = mi*16+quad*4+r.
// P kept packed bf16 in regs (unnormalized) for attn write; staged in padded LDS for PV.
// PV: ctx^T[d][q] = mfma(V^T, P); normalize both outputs by 1/rowsum at the end.
__global__ __launch_bounds__(256) void attn_fused_k(const u16* __restrict__ qkvb,
                                                    const u16* __restrict__ vtb,
                                                    float* __restrict__ attn,
                                                    u16* __restrict__ ctxb) {
  __shared__ __align__(128) u16 Ks[128 * 64];   // swizzled K chunk [128 s][64 d], 16KB
  __shared__ __align__(128) u16 Vs[64 * 128];   // swizzled V^T chunk [64 d][128 s], 16KB
  __shared__ __align__(128) u16 Ps[64 * 136];   // padded P [64 q][136], 17KB
  __shared__ float invs[64];

  const int tid = threadIdx.x;
  const int lane = tid & 63;
  const int w = tid >> 6;
  const int quad = lane >> 4, l16 = lane & 15;

  const int z = blockIdx.y;
  const int b = z >> 4, h = z & 15;
  const u16* Kt = qkvb + (long)b * 3145728 + 1024 + h * 64;
  const u16* Vt = vtb + (long)z * 65536;

  const int qabs = blockIdx.x * 64 + w * 16 + l16;  // q row within seq
  const long qrow = ((long)b * 1024 + qabs) * 3072 + h * 64;

  bf16x8 qf0 = *(const bf16x8*)&qkvb[qrow + quad * 8];
  bf16x8 qf1 = *(const bf16x8*)&qkvb[qrow + 32 + quad * 8];

  unsigned p[8][8][2];  // packed bf16 exp, [chunk][mi][pair] (static idx via unroll)
  float rowsum = 0.f;
  f32x4 cacc[4] = {};   // ctx^T acc per ni

  const int klr = lane >> 3;
  const int klc = 8 * ((lane & 7) ^ (lane >> 3));      // K staging swizzled col (elems)
  const int vrow_in = lane >> 4;

#pragma unroll
  for (int nc = 0; nc < 8; ++nc) {
    // stage K rows [nc*128, +128) x 64 dims (swizzled via global src)
#pragma unroll
    for (int c = 0; c < 4; ++c) {
      int ch = c * 4 + w;
      gload16(Kt + (long)(nc * 128 + ch * 8 + klr) * 3072 + klc, &Ks[ch * 512]);
    }
    // stage V^T rows [0,64) x s cols [nc*128, +128) (swizzled via global src)
#pragma unroll
    for (int c = 0; c < 4; ++c) {
      int ch = c * 4 + w;
      int vr = ch * 4 + vrow_in;
      int vc = 8 * ((lane & 15) ^ (vr & 7));
      gload16(Vt + (long)vr * 1024 + nc * 128 + vc, &Vs[ch * 512]);
    }
    __syncthreads();

    // QK^T + exp + pack + P->LDS
#pragma unroll
    for (int mi = 0; mi < 8; ++mi) {
      int R = mi * 16 + l16;
      bf16x8 kf0 = *(const bf16x8*)&Ks[R * 64 + 8 * (quad ^ (l16 & 7))];
      bf16x8 kf1 = *(const bf16x8*)&Ks[R * 64 + 8 * ((4 + quad) ^ (l16 & 7))];
      f32x4 acc = {};
      acc = __builtin_amdgcn_mfma_f32_16x16x32_bf16(kf0, qf0, acc, 0, 0, 0);
      acc = __builtin_amdgcn_mfma_f32_16x16x32_bf16(kf1, qf1, acc, 0, 0, 0);
      float e0 = __expf(acc[0] * 0.125f);
      float e1 = __expf(acc[1] * 0.125f);
      float e2 = __expf(acc[2] * 0.125f);
      float e3 = __expf(acc[3] * 0.125f);
      rowsum += (e0 + e1) + (e2 + e3);
      unsigned p0 = (unsigned)f2b(e0) | ((unsigned)f2b(e1) << 16);
      unsigned p1 = (unsigned)f2b(e2) | ((unsigned)f2b(e3) << 16);
      p[nc][mi][0] = p0;
      p[nc][mi][1] = p1;
      *(uint2*)&Ps[(w * 16 + l16) * 136 + mi * 16 + quad * 4] = make_uint2(p0, p1);
    }
    __syncthreads();  // Ps visible to all waves

    // PV: ctx^T[d][q] += V^T x P
    {
      int VR = w * 16 + l16;  // d row
#pragma unroll
      for (int ks = 0; ks < 4; ++ks) {
        bf16x8 vf = *(const bf16x8*)&Vs[VR * 128 + 8 * ((ks * 4 + quad) ^ (l16 & 7))];
#pragma unroll
        for (int ni = 0; ni < 4; ++ni) {
          bf16x8 pf = *(const bf16x8*)&Ps[(ni * 16 + l16) * 136 + ks * 32 + quad * 8];
          cacc[ni] = __builtin_amdgcn_mfma_f32_16x16x32_bf16(vf, pf, cacc[ni], 0, 0, 0);
        }
      }
    }
    __syncthreads();  // before next chunk overwrites Ks/Vs/Ps
  }

  // rowsum: lanes sharing l16 across 4 quads hold complementary k partials
  rowsum += __shfl_xor(rowsum, 16);
  rowsum += __shfl_xor(rowsum, 32);
  float inv = 1.f / rowsum;
  if (quad == 0) invs[w * 16 + l16] = inv;
  __syncthreads();

  // ctx^T -> ctx via LDS transpose (reuse Ks), normalized, bf16
  u16* ctx_lds = Ks;  // [64 q][72 d] padded
#pragma unroll
  for (int ni = 0; ni < 4; ++ni) {
    float iv = invs[ni * 16 + l16];
    unsigned c01 = (unsigned)f2b(cacc[ni][0] * iv) | ((unsigned)f2b(cacc[ni][1] * iv) << 16);
    unsigned c23 = (unsigned)f2b(cacc[ni][2] * iv) | ((unsigned)f2b(cacc[ni][3] * iv) << 16);
    *(uint2*)&ctx_lds[(ni * 16 + l16) * 72 + w * 16 + quad * 4] = make_uint2(c01, c23);
  }
  __syncthreads();
#pragma unroll
  for (int i = 0; i < 2; ++i) {
    int q = w * 16 + (lane >> 3) + i * 8;
    int d0 = (lane & 7) * 8;
    bf16x8 cv = *(const bf16x8*)&ctx_lds[q * 72 + d0];
    long tok = (long)b * 1024 + blockIdx.x * 64 + q;
    *(bf16x8*)&ctxb[tok * 1024 + h * 64 + d0] = cv;
  }

  // attn fp32 write straight from registers (64B bursts per row)
  const long arow = ((long)z * 1024 + qabs) * 1024;
#pragma unroll
  for (int nc = 0; nc < 8; ++nc) {
#pragma unroll
    for (int mi = 0; mi < 8; ++mi) {
      float4 v;
      v.x = b2f((u16)(p[nc][mi][0] & 0xffff)) * inv;
      v.y = b2f((u16)(p[nc][mi][0] >> 16)) * inv;
      v.z = b2f((u16)(p[nc][mi][1] & 0xffff)) * inv;
      v.w = b2f((u16)(p[nc][mi][1] >> 16)) * inv;
      *(float4*)&attn[arow + nc * 128 + mi * 16 + quad * 4] = v;
    }
  }
}

// ---------------- residual(+)/layernorm, row of 1024 ----------------
template <int WB16, int ADD>
__global__ __launch_bounds__(256) void add_ln_k(const float* __restrict__ xp,
                                                const float* __restrict__ yp,
                                                const float* __restrict__ g,
                                                const float* __restrict__ bta,
                                                float* __restrict__ of,
                                                u16* __restrict__ ob) {
  long row = blockIdx.x;
  int tid = threadIdx.x;
  float4 v = *(const float4*)(xp + row * 1024 + tid * 4);
  if (ADD) {
    const float4 yv = *(const float4*)(yp + row * 1024 + tid * 4);
    v.x += yv.x; v.y += yv.y; v.z += yv.z; v.w += yv.w;
  }
  float s1 = v.x + v.y + v.z + v.w;
  float s2 = v.x * v.x + v.y * v.y + v.z * v.z + v.w * v.w;
#pragma unroll
  for (int d = 32; d > 0; d >>= 1) {
    s1 += __shfl_xor(s1, d);
    s2 += __shfl_xor(s2, d);
  }
  __shared__ float r1[4], r2[4];
  if ((tid & 63) == 0) { r1[tid >> 6] = s1; r2[tid >> 6] = s2; }
  __syncthreads();
  s1 = r1[0] + r1[1] + r1[2] + r1[3];
  s2 = r2[0] + r2[1] + r2[2] + r2[3];
  float mu = s1 * (1.f / 1024.f);
  float var = s2 * (1.f / 1024.f) - mu * mu;
  float rs = rsqrtf(var + 1e-5f);
  float4 gv = *(const float4*)(g + tid * 4);
  float4 bv = *(const float4*)(bta + tid * 4);
  float4 o;
  o.x = (v.x - mu) * rs * gv.x + bv.x;
  o.y = (v.y - mu) * rs * gv.y + bv.y;
  o.z = (v.z - mu) * rs * gv.z + bv.z;
  o.w = (v.w - mu) * rs * gv.w + bv.w;
  *(float4*)(of + row * 1024 + tid * 4) = o;
  if (WB16) {
    ushort4 ov = make_ushort4(f2b(o.x), f2b(o.y), f2b(o.z), f2b(o.w));
    *(ushort4*)(ob + row * 1024 + tid * 4) = ov;
  }
}

extern "C" void kernel_launch(void* const* d_in, const int* in_sizes, int n_in,
                              void* d_out, int out_size, void* d_ws, size_t ws_size,
                              hipStream_t stream) {
  const float* x   = (const float*)d_in[0];
  const float* Wq  = (const float*)d_in[1];
  const float* bq  = (const float*)d_in[2];
  const float* Wk  = (const float*)d_in[3];
  const float* bk  = (const float*)d_in[4];
  const float* Wv  = (const float*)d_in[5];
  const float* bv  = (const float*)d_in[6];
  const float* Wo  = (const float*)d_in[7];
  const float* bo  = (const float*)d_in[8];
  const float* W1  = (const float*)d_in[9];
  const float* b1  = (const float*)d_in[10];
  const float* W2  = (const float*)d_in[11];
  const float* b2  = (const float*)d_in[12];
  const float* g1  = (const float*)d_in[13];
  const float* be1 = (const float*)d_in[14];
  const float* g2  = (const float*)d_in[15];
  const float* be2 = (const float*)d_in[16];

  float* out = (float*)d_out;
  float* attn = out + 4194304LL;  // [4,16,1024,1024] fp32 (post-softmax weights)

  char* w = (char*)d_ws;
  size_t off = 0;
  auto alloc = [&](size_t bytes) {
    void* p = w + off;
    off = (off + bytes + 255) & ~(size_t)255;
    return p;
  };
  u16* xb        = (u16*)alloc(8388608);     // x bf16 [4096,1024]
  u16* Wqkvt     = (u16*)alloc(6291456);     // [3072,1024] bf16
  u16* Wot       = (u16*)alloc(2097152);
  u16* W1t       = (u16*)alloc(8388608);
  u16* W2t       = (u16*)alloc(8388608);
  u16* qkvb      = (u16*)alloc(25165824);    // [4096,3072] bf16
  u16* vtb       = (u16*)alloc(8388608);     // [64,64,1024] bf16
  u16* ctxb      = (u16*)alloc(8388608);     // [4096,1024] bf16
  float* attn_o  = (float*)alloc(16777216);  // ctx Wo + bo + x
  float* x1      = (float*)alloc(16777216);
  u16* x1b       = (u16*)alloc(8388608);
  u16* ff1b      = (u16*)alloc(33554432);
  float* ff2     = (float*)alloc(16777216);  // ff1 W2 + b2 + x1
  (void)ws_size; (void)in_sizes; (void)n_in; (void)out_size;

  // 1) merged prep
  prep_k<<<16384, 256, 0, stream>>>(x, xb, Wq, Wk, Wv, Wo, W1, W2, Wqkvt, Wot, W1t, W2t);

  // 2) QKV projection
  gemm_k<128, 3, 0, 1, 0, 0><<<dim3(24, 32, 1), 256, 0, stream>>>(
      xb, 0, 0, 1024, Wqkvt, 0, 0, 1024,
      nullptr, qkvb, 0, 0, 3072, bq, bk, bv, nullptr, 1024, 1);

  // 3) V head-transpose
  transpose_v_k<<<dim3(32, 2, 64), dim3(32, 8), 0, stream>>>(qkvb, vtb);

  // 4) fused attention: scores+softmax+PV -> attn fp32 + ctxb bf16
  attn_fused_k<<<dim3(16, 64), 256, 0, stream>>>(qkvb, vtb, attn, ctxb);

  // 5) attn_o = ctx Wo + bo + x
  gemm_k<64, 1, 0, 0, 1, 1><<<dim3(16, 32, 1), 256, 0, stream>>>(
      ctxb, 0, 0, 1024, Wot, 0, 0, 1024,
      attn_o, nullptr, 0, 0, 1024, bo, nullptr, nullptr, x, 1024, 1);

  // 6) x1 = LN(attn_o)
  add_ln_k<1, 0><<<4096, 256, 0, stream>>>(attn_o, nullptr, g1, be1, x1, x1b);

  // 7) ff1 = relu(x1 W1 + b1)
  gemm_k<128, 1, 1, 1, 0, 0><<<dim3(32, 32, 1), 256, 0, stream>>>(
      x1b, 0, 0, 1024, W1t, 0, 0, 1024,
      nullptr, ff1b, 0, 0, 4096, b1, nullptr, nullptr, nullptr, 1024, 1);

  // 8) ff2 = ff1 W2 + b2 + x1
  gemm_k<64, 1, 0, 0, 1, 1><<<dim3(16, 32, 1), 256, 0, stream>>>(
      ff1b, 0, 0, 4096, W2t, 0, 0, 4096,
      ff2, nullptr, 0, 0, 1024, b2, nullptr, nullptr, x1, 4096, 1);

  // 9) out = LN(ff2)
  add_ln_k<0, 0><<<4096, 256, 0, stream>>>(ff2, nullptr, g2, be2, out, nullptr);
}